// Round 11
// baseline (3604.565 us; speedup 1.0000x reference)
//
#include <hip/hip_runtime.h>
#include <hip/hip_bf16.h>

typedef __attribute__((ext_vector_type(8))) short  short8;   // 8 x bf16 (MFMA frag)
typedef __attribute__((ext_vector_type(4))) float  f32x4;
typedef __attribute__((ext_vector_type(2))) unsigned int uint2v;
typedef unsigned long long u64;

#define NSTEPS 100
#define HSTEP  0.2f

// ---- RK45 (Dormand-Prince) coefficients ----
#define A21 (0.2f)
#define A31 (3.0f/40.0f)
#define A32 (9.0f/40.0f)
#define A41 (44.0f/45.0f)
#define A42 (-56.0f/15.0f)
#define A43 (32.0f/9.0f)
#define A51 (19372.0f/6561.0f)
#define A52 (-25360.0f/2187.0f)
#define A53 (64448.0f/6561.0f)
#define A54 (-212.0f/729.0f)
#define A61 (9017.0f/3168.0f)
#define A62 (-355.0f/33.0f)
#define A63 (46732.0f/5247.0f)
#define A64 (49.0f/176.0f)
#define A65 (-5103.0f/18656.0f)
#define B1  (35.0f/384.0f)
#define B3  (500.0f/1113.0f)
#define B4  (125.0f/192.0f)
#define B5  (-2187.0f/6784.0f)
#define B6  (11.0f/84.0f)

// d_ws layout (bytes):
//   [0,      512K)   Aw   : bf16 A in MFMA-frag order
//   [512K,   +8K )   sctr : 64 counters, 128B apart (memset 0 each launch)
//   [1M,     3M  )   Ybuf : 2 parity x 64 g x 4 q x 4KB bf16 Y-slices
#define WS_SCTR (512u * 1024u)
#define WS_YB   (1024u * 1024u)

__device__ __forceinline__ unsigned short f2bf(float f) {
    union { float f; unsigned u; } v; v.f = f;
    unsigned r = v.u + 0x7FFFu + ((v.u >> 16) & 1u);   // RNE
    return (unsigned short)(r >> 16);
}

// Pack A (f32 row-major [row][k]) into bf16 MFMA A-fragment stream order:
// slot fk = T*16+kk, lane: holds A[T*16 + (lane&15)][kk*32 + (lane>>4)*8 + 0..7]
__global__ void pack_A_kernel(const float* __restrict__ A, short* __restrict__ Aw) {
    int t    = blockIdx.x * blockDim.x + threadIdx.x;   // 0..32767
    int lane = t & 63;
    int fk   = t >> 6;
    int kk   = fk & 15;
    int T    = fk >> 4;
    int row  = T * 16 + (lane & 15);
    int kb   = kk * 32 + (lane >> 4) * 8;
    const float* src = A + row * 512 + kb;
    short8 v;
#pragma unroll
    for (int e = 0; e < 8; ++e) v[e] = (short)f2bf(src[e]);
    *(short8*)(Aw + (size_t)t * 8) = v;
}

__global__ __launch_bounds__(512, 1) void mbpert_kernel(
    const float* __restrict__ x, const float* __restrict__ p,
    const float* __restrict__ r, const float* __restrict__ eps,
    const short* __restrict__ Aw, unsigned* __restrict__ sctr,
    u64* __restrict__ Ybuf, float* __restrict__ out)
{
    __shared__ __align__(16) char Ylds[2][16 * 1024];  // double-buffered Y (bf16, swizzled)

    const int bid  = blockIdx.x;
    const int g    = bid >> 2;        // column group: cols [g*16, g*16+16)
    const int q    = bid & 3;         // row quarter: rows [q*128, q*128+128)
    const int tid  = threadIdx.x;
    const int wave = tid >> 6;
    const int lane = tid & 63;
    const int cl   = lane & 15;
    const int gq   = lane >> 4;
    const int col  = g * 16 + cl;
    const int swz  = (cl & 7) << 4;
    const int rloc = wave * 16 + gq * 4;   // local row base (0..127)
    const int rg   = q * 128 + rloc;       // global row base

    unsigned* cptr = sctr + g * 32;   // group counter, 128B padded

    // ---- A-fragments into registers once (compiler parks them in AGPRs);
    // pin with opaque asm so they can't be re-loaded per stage ----
    short8 afrag[16];
    {
        const int T = q * 8 + wave;    // global 16-row tile owned by this wave
#pragma unroll
        for (int kk = 0; kk < 16; ++kk)
            afrag[kk] = *(const short8*)(Aw + ((size_t)(T * 16 + kk) * 64 + lane) * 8);
#pragma unroll
        for (int kk = 0; kk < 16; ++kk)
            asm volatile("" : "+v"(afrag[kk]));
    }

    // ---- per-thread state: 4 rows x 1 col ----
    f32x4 X0, W;
    X0 = *(const f32x4*)(x + col * 512 + rg);     // Fortran x[col*512+row]
#pragma unroll
    for (int j = 0; j < 4; ++j) {
        const int row = rg + j;
        W[j] = r[row] + eps[row] * p[row * 1024 + col];
    }

    int ex = 0;   // exchange index 0..599

    // One RK stage. R6-proven sync skeleton (barrier / tid0 RMW / wave0-only
    // spin / barrier) + own-K MFMA overlap + double-buffered Ylds (no tail
    // barrier: 3 collective barriers order stage s+2 writes after stage s reads).
    auto STAGE = [&](f32x4 Yv) -> f32x4 {
        char* buf = Ylds[ex & 1];
        auto bfrag = [&](int kk) -> short8 {
            return *(const short8*)(buf + cl * 1024 + ((kk * 64 + gq * 16) ^ swz));
        };

        unsigned lo = (unsigned)f2bf(Yv[0]) | ((unsigned)f2bf(Yv[1]) << 16);
        unsigned hi = (unsigned)f2bf(Yv[2]) | ((unsigned)f2bf(Yv[3]) << 16);
        uint2v u; u.x = lo; u.y = hi;
        *(uint2v*)(buf + cl * 1024 + ((rg * 2) ^ swz)) = u;        // own -> Ylds
        u64* slot = Ybuf + ((size_t)((ex & 1) * 64 + g) * 4 + q) * 512;
        __hip_atomic_store(slot + (cl * 32 + (rloc >> 2)),
                           (u64)lo | ((u64)hi << 32),
                           __ATOMIC_RELAXED, __HIP_MEMORY_SCOPE_AGENT);
        asm volatile("s_waitcnt vmcnt(0)" ::: "memory");   // own 8B at LLC
        __syncthreads();                                   // #1: drains + own Ylds rows
        if (tid == 0) atomicAdd(cptr, 1u);

        // ---- own-K overlap: 4 chunks covering our own 128 rows (in buf now) ----
        f32x4 acc = (f32x4){0.f, 0.f, 0.f, 0.f};
#pragma unroll
        for (int kk = q * 4; kk < q * 4 + 4; ++kk)
            acc = __builtin_amdgcn_mfma_f32_16x16x32_bf16(afrag[kk], bfrag(kk), acc, 0, 0, 0);

        const unsigned tgt = 4u * (unsigned)(ex + 1);
        if (wave == 0) {                                   // single spinner per WG
            while (__hip_atomic_load(cptr, __ATOMIC_RELAXED, __HIP_MEMORY_SCOPE_AGENT) < tgt)
                __builtin_amdgcn_s_sleep(1);
        }
        __syncthreads();                                   // #2: all peers published
        asm volatile("" ::: "memory");

        // pull 3 peers' 4KB slices (32 consecutive tids = 256B coalesced run)
        const int pcol = tid >> 5, prq = tid & 31;
        const u64* pb = Ybuf + (size_t)((ex & 1) * 64 + g) * 4 * 512;
#pragma unroll
        for (int j = 1; j <= 3; ++j) {
            const int qq = (q + j) & 3;
            u64 v = __hip_atomic_load(pb + qq * 512 + pcol * 32 + prq,
                                      __ATOMIC_RELAXED, __HIP_MEMORY_SCOPE_AGENT);
            uint2v w; w.x = (unsigned)v; w.y = (unsigned)(v >> 32);
            const int prg = qq * 128 + prq * 4;
            *(uint2v*)(buf + pcol * 1024 + ((prg * 2) ^ ((pcol & 7) << 4))) = w;
        }
        __syncthreads();                                   // #3: full Y in buf

        // remaining 12 K-chunks (peer rows)
#pragma unroll
        for (int j = 1; j <= 3; ++j) {
            const int qq = (q + j) & 3;
#pragma unroll
            for (int kk = qq * 4; kk < qq * 4 + 4; ++kk)
                acc = __builtin_amdgcn_mfma_f32_16x16x32_bf16(afrag[kk], bfrag(kk), acc, 0, 0, 0);
        }
        ++ex;
        return Yv * (W + acc);
    };

#pragma unroll 1
    for (int s = 0; s < NSTEPS; ++s) {
        f32x4 K1 = STAGE(X0);
        f32x4 K2 = STAGE(X0 + HSTEP * (A21 * K1));
        f32x4 K3 = STAGE(X0 + HSTEP * (A31 * K1 + A32 * K2));
        f32x4 K4 = STAGE(X0 + HSTEP * (A41 * K1 + A42 * K2 + A43 * K3));
        f32x4 K5 = STAGE(X0 + HSTEP * (A51 * K1 + A52 * K2 + A53 * K3 + A54 * K4));
        f32x4 K6 = STAGE(X0 + HSTEP * (A61 * K1 + A62 * K2 + A63 * K3 + A64 * K4 + A65 * K5));
        X0 = X0 + HSTEP * (B1 * K1 + B3 * K3 + B4 * K4 + B5 * K5 + B6 * K6);
    }

    // Fortran flatten: out[col*512 + row]
    *(f32x4*)(out + col * 512 + rg) = X0;
}

extern "C" void kernel_launch(void* const* d_in, const int* in_sizes, int n_in,
                              void* d_out, int out_size, void* d_ws, size_t ws_size,
                              hipStream_t stream)
{
    const float* x   = (const float*)d_in[0];
    const float* p   = (const float*)d_in[1];
    const float* r   = (const float*)d_in[2];
    const float* A   = (const float*)d_in[3];
    const float* eps = (const float*)d_in[4];
    float* out = (float*)d_out;

    short*    Aw   = (short*)d_ws;
    unsigned* sctr = (unsigned*)((char*)d_ws + WS_SCTR);
    u64*      Ybuf = (u64*)((char*)d_ws + WS_YB);

    hipMemsetAsync(sctr, 0, 8192, stream);                  // zero group counters
    hipLaunchKernelGGL(pack_A_kernel, dim3(128), dim3(256), 0, stream, A, Aw);
    hipLaunchKernelGGL(mbpert_kernel, dim3(256), dim3(512), 0, stream,
                       x, p, r, eps, Aw, sctr, Ybuf, out);
}

// Round 12
// 1589.165 us; speedup vs baseline: 2.2682x; 2.2682x over previous
//
#include <hip/hip_runtime.h>
#include <hip/hip_bf16.h>

typedef __attribute__((ext_vector_type(8))) short  short8;   // 8 x bf16 (MFMA frag)
typedef __attribute__((ext_vector_type(4))) float  f32x4;
typedef __attribute__((ext_vector_type(2))) unsigned int uint2v;
typedef unsigned long long u64;

#define NSTEPS 100
#define HSTEP  0.2f

// ---- RK45 (Dormand-Prince) coefficients ----
#define A21 (0.2f)
#define A31 (3.0f/40.0f)
#define A32 (9.0f/40.0f)
#define A41 (44.0f/45.0f)
#define A42 (-56.0f/15.0f)
#define A43 (32.0f/9.0f)
#define A51 (19372.0f/6561.0f)
#define A52 (-25360.0f/2187.0f)
#define A53 (64448.0f/6561.0f)
#define A54 (-212.0f/729.0f)
#define A61 (9017.0f/3168.0f)
#define A62 (-355.0f/33.0f)
#define A63 (46732.0f/5247.0f)
#define A64 (49.0f/176.0f)
#define A65 (-5103.0f/18656.0f)
#define B1  (35.0f/384.0f)
#define B3  (500.0f/1113.0f)
#define B4  (125.0f/192.0f)
#define B5  (-2187.0f/6784.0f)
#define B6  (11.0f/84.0f)

// d_ws layout (bytes):
//   [0,      512K)   Aw   : bf16 A in MFMA-frag order
//   [512K,   +8K )   sctr : 64 counters, 128B apart (memset 0 each launch)
//   [1M,     3M  )   Ybuf : 2 parity x 64 g x 4 q x 4KB bf16 Y-slices
#define WS_SCTR (512u * 1024u)
#define WS_YB   (1024u * 1024u)

__device__ __forceinline__ unsigned short f2bf(float f) {
    union { float f; unsigned u; } v; v.f = f;
    unsigned r = v.u + 0x7FFFu + ((v.u >> 16) & 1u);   // RNE
    return (unsigned short)(r >> 16);
}

// Pack A (f32 row-major [row][k]) into bf16 MFMA A-fragment stream order:
// slot fk = T*16+kk, lane: holds A[T*16 + (lane&15)][kk*32 + (lane>>4)*8 + 0..7]
__global__ void pack_A_kernel(const float* __restrict__ A, short* __restrict__ Aw) {
    int t    = blockIdx.x * blockDim.x + threadIdx.x;   // 0..32767
    int lane = t & 63;
    int fk   = t >> 6;
    int kk   = fk & 15;
    int T    = fk >> 4;
    int row  = T * 16 + (lane & 15);
    int kb   = kk * 32 + (lane >> 4) * 8;
    const float* src = A + row * 512 + kb;
    short8 v;
#pragma unroll
    for (int e = 0; e < 8; ++e) v[e] = (short)f2bf(src[e]);
    *(short8*)(Aw + (size_t)t * 8) = v;
}

__global__ __launch_bounds__(512, 1) void mbpert_kernel(
    const float* __restrict__ x, const float* __restrict__ p,
    const float* __restrict__ r, const float* __restrict__ eps,
    const short* __restrict__ Aw, unsigned* __restrict__ sctr,
    u64* __restrict__ Ybuf, float* __restrict__ out)
{
    __shared__ __align__(16) char Ylds[2][16 * 1024];  // double-buffered Y (bf16, swizzled)

    const int bid  = blockIdx.x;
    const int g    = bid >> 2;        // column group: cols [g*16, g*16+16)
    const int q    = bid & 3;         // row quarter: rows [q*128, q*128+128)
    const int tid  = threadIdx.x;
    const int wave = tid >> 6;
    const int lane = tid & 63;
    const int cl   = lane & 15;
    const int gq   = lane >> 4;
    const int col  = g * 16 + cl;
    const int swz  = (cl & 7) << 4;
    const int rloc = wave * 16 + gq * 4;   // local row base (0..127)
    const int rg   = q * 128 + rloc;       // global row base

    unsigned* cptr = sctr + g * 32;   // group counter, 128B padded

    // ---- A-fragments into registers once, in LOGICAL (own-first) chunk order:
    // logical l <-> physical K-chunk (4q + l) & 15. Every afrag[] access below
    // uses a LITERAL index (rule #20: runtime-indexed arrays go to scratch —
    // R11's 7.4GB FETCH regression). The runtime q lives only in addresses.
    short8 afrag[16];
    {
        const int T = q * 8 + wave;    // global 16-row tile owned by this wave
#pragma unroll
        for (int l = 0; l < 16; ++l) {
            const int kphys = (4 * q + l) & 15;
            afrag[l] = *(const short8*)(Aw + ((size_t)(T * 16 + kphys) * 64 + lane) * 8);
        }
#pragma unroll
        for (int l = 0; l < 16; ++l)
            asm volatile("" : "+v"(afrag[l]));   // pin: no re-load, no remat
    }

    // ---- per-thread state: 4 rows x 1 col ----
    f32x4 X0, W;
    X0 = *(const f32x4*)(x + col * 512 + rg);     // Fortran x[col*512+row]
#pragma unroll
    for (int j = 0; j < 4; ++j) {
        const int row = rg + j;
        W[j] = r[row] + eps[row] * p[row * 1024 + col];
    }

    int ex = 0;   // exchange index 0..599

    // One RK stage. R6-proven sync skeleton (barrier / tid0 RMW / wave0-only
    // spin / barrier) + own-K MFMA overlap + double-buffered Ylds (no tail
    // barrier: 3 collective barriers order stage s+2 writes after stage s reads).
    auto STAGE = [&](f32x4 Yv) -> f32x4 {
        char* buf = Ylds[ex & 1];
        // B-fragment for LOGICAL chunk l (physical (4q+l)&15); l is literal.
        auto bfrag = [&](int l) -> short8 {
            const int kphys = (4 * q + l) & 15;
            return *(const short8*)(buf + cl * 1024 + ((kphys * 64 + gq * 16) ^ swz));
        };

        unsigned lo = (unsigned)f2bf(Yv[0]) | ((unsigned)f2bf(Yv[1]) << 16);
        unsigned hi = (unsigned)f2bf(Yv[2]) | ((unsigned)f2bf(Yv[3]) << 16);
        uint2v u; u.x = lo; u.y = hi;
        *(uint2v*)(buf + cl * 1024 + ((rg * 2) ^ swz)) = u;        // own -> Ylds
        u64* slot = Ybuf + ((size_t)((ex & 1) * 64 + g) * 4 + q) * 512;
        __hip_atomic_store(slot + (cl * 32 + (rloc >> 2)),
                           (u64)lo | ((u64)hi << 32),
                           __ATOMIC_RELAXED, __HIP_MEMORY_SCOPE_AGENT);
        asm volatile("s_waitcnt vmcnt(0)" ::: "memory");   // own 8B at LLC
        __syncthreads();                                   // #1: drains + own Ylds rows
        if (tid == 0) atomicAdd(cptr, 1u);

        // ---- own-K overlap: logical chunks 0..3 = our own 128 rows (in buf) ----
        f32x4 acc = (f32x4){0.f, 0.f, 0.f, 0.f};
#pragma unroll
        for (int l = 0; l < 4; ++l)
            acc = __builtin_amdgcn_mfma_f32_16x16x32_bf16(afrag[l], bfrag(l), acc, 0, 0, 0);

        const unsigned tgt = 4u * (unsigned)(ex + 1);
        if (wave == 0) {                                   // single spinner per WG
            while (__hip_atomic_load(cptr, __ATOMIC_RELAXED, __HIP_MEMORY_SCOPE_AGENT) < tgt)
                __builtin_amdgcn_s_sleep(1);
        }
        __syncthreads();                                   // #2: all peers published
        asm volatile("" ::: "memory");

        // pull 3 peers' 4KB slices (32 consecutive tids = 256B coalesced run)
        const int pcol = tid >> 5, prq = tid & 31;
        const u64* pb = Ybuf + (size_t)((ex & 1) * 64 + g) * 4 * 512;
#pragma unroll
        for (int j = 1; j <= 3; ++j) {
            const int qq = (q + j) & 3;
            u64 v = __hip_atomic_load(pb + qq * 512 + pcol * 32 + prq,
                                      __ATOMIC_RELAXED, __HIP_MEMORY_SCOPE_AGENT);
            uint2v w; w.x = (unsigned)v; w.y = (unsigned)(v >> 32);
            const int prg = qq * 128 + prq * 4;
            *(uint2v*)(buf + pcol * 1024 + ((prg * 2) ^ ((pcol & 7) << 4))) = w;
        }
        __syncthreads();                                   // #3: full Y in buf

        // remaining 12 logical chunks (peer rows), literal indices 4..15
#pragma unroll
        for (int l = 4; l < 16; ++l)
            acc = __builtin_amdgcn_mfma_f32_16x16x32_bf16(afrag[l], bfrag(l), acc, 0, 0, 0);
        ++ex;
        return Yv * (W + acc);
    };

#pragma unroll 1
    for (int s = 0; s < NSTEPS; ++s) {
        f32x4 K1 = STAGE(X0);
        f32x4 K2 = STAGE(X0 + HSTEP * (A21 * K1));
        f32x4 K3 = STAGE(X0 + HSTEP * (A31 * K1 + A32 * K2));
        f32x4 K4 = STAGE(X0 + HSTEP * (A41 * K1 + A42 * K2 + A43 * K3));
        f32x4 K5 = STAGE(X0 + HSTEP * (A51 * K1 + A52 * K2 + A53 * K3 + A54 * K4));
        f32x4 K6 = STAGE(X0 + HSTEP * (A61 * K1 + A62 * K2 + A63 * K3 + A64 * K4 + A65 * K5));
        X0 = X0 + HSTEP * (B1 * K1 + B3 * K3 + B4 * K4 + B5 * K5 + B6 * K6);
    }

    // Fortran flatten: out[col*512 + row]
    *(f32x4*)(out + col * 512 + rg) = X0;
}

extern "C" void kernel_launch(void* const* d_in, const int* in_sizes, int n_in,
                              void* d_out, int out_size, void* d_ws, size_t ws_size,
                              hipStream_t stream)
{
    const float* x   = (const float*)d_in[0];
    const float* p   = (const float*)d_in[1];
    const float* r   = (const float*)d_in[2];
    const float* A   = (const float*)d_in[3];
    const float* eps = (const float*)d_in[4];
    float* out = (float*)d_out;

    short*    Aw   = (short*)d_ws;
    unsigned* sctr = (unsigned*)((char*)d_ws + WS_SCTR);
    u64*      Ybuf = (u64*)((char*)d_ws + WS_YB);

    hipMemsetAsync(sctr, 0, 8192, stream);                  // zero group counters
    hipLaunchKernelGGL(pack_A_kernel, dim3(128), dim3(256), 0, stream, A, Aw);
    hipLaunchKernelGGL(mbpert_kernel, dim3(256), dim3(512), 0, stream,
                       x, p, r, eps, Aw, sctr, Ybuf, out);
}

// Round 13
// 1200.963 us; speedup vs baseline: 3.0014x; 1.3232x over previous
//
#include <hip/hip_runtime.h>
#include <hip/hip_bf16.h>

typedef __attribute__((ext_vector_type(8))) short  short8;   // 8 x bf16 (MFMA frag)
typedef __attribute__((ext_vector_type(4))) float  f32x4;
typedef __attribute__((ext_vector_type(2))) unsigned int uint2v;
typedef unsigned long long u64;

#define NSTEPS 100
#define HSTEP  0.2f

// ---- RK45 (Dormand-Prince) coefficients ----
#define A21 (0.2f)
#define A31 (3.0f/40.0f)
#define A32 (9.0f/40.0f)
#define A41 (44.0f/45.0f)
#define A42 (-56.0f/15.0f)
#define A43 (32.0f/9.0f)
#define A51 (19372.0f/6561.0f)
#define A52 (-25360.0f/2187.0f)
#define A53 (64448.0f/6561.0f)
#define A54 (-212.0f/729.0f)
#define A61 (9017.0f/3168.0f)
#define A62 (-355.0f/33.0f)
#define A63 (46732.0f/5247.0f)
#define A64 (49.0f/176.0f)
#define A65 (-5103.0f/18656.0f)
#define B1  (35.0f/384.0f)
#define B3  (500.0f/1113.0f)
#define B4  (125.0f/192.0f)
#define B5  (-2187.0f/6784.0f)
#define B6  (11.0f/84.0f)

// d_ws layout (bytes):
//   [0,      512K)   Aw   : bf16 A in MFMA-frag order
//   [512K,   +8K )   flg  : 64 groups x 128B flag lines, words [0..3]=q (memset 0)
//   [1M,     3M  )   Ybuf : 2 parity x 64 g x 4 q x 4KB bf16 Y-slices
#define WS_FLG  (512u * 1024u)
#define WS_YB   (1024u * 1024u)

__device__ __forceinline__ unsigned short f2bf(float f) {
    union { float f; unsigned u; } v; v.f = f;
    unsigned r = v.u + 0x7FFFu + ((v.u >> 16) & 1u);   // RNE
    return (unsigned short)(r >> 16);
}

// Pack A (f32 row-major [row][k]) into bf16 MFMA A-fragment stream order:
// slot fk = T*16+kk, lane: holds A[T*16 + (lane&15)][kk*32 + (lane>>4)*8 + 0..7]
__global__ void pack_A_kernel(const float* __restrict__ A, short* __restrict__ Aw) {
    int t    = blockIdx.x * blockDim.x + threadIdx.x;   // 0..32767
    int lane = t & 63;
    int fk   = t >> 6;
    int kk   = fk & 15;
    int T    = fk >> 4;
    int row  = T * 16 + (lane & 15);
    int kb   = kk * 32 + (lane >> 4) * 8;
    const float* src = A + row * 512 + kb;
    short8 v;
#pragma unroll
    for (int e = 0; e < 8; ++e) v[e] = (short)f2bf(src[e]);
    *(short8*)(Aw + (size_t)t * 8) = v;
}

__global__ __launch_bounds__(512, 1) void mbpert_kernel(
    const float* __restrict__ x, const float* __restrict__ p,
    const float* __restrict__ r, const float* __restrict__ eps,
    const short* __restrict__ Aw, unsigned* __restrict__ flg,
    u64* __restrict__ Ybuf, float* __restrict__ out)
{
    __shared__ __align__(16) char Ylds[2][16 * 1024];  // double-buffered Y (bf16, swizzled)

    const int bid  = blockIdx.x;
    const int g    = bid >> 2;        // column group: cols [g*16, g*16+16)
    const int q    = bid & 3;         // row quarter: rows [q*128, q*128+128)
    const int tid  = threadIdx.x;
    const int wave = tid >> 6;
    const int lane = tid & 63;
    const int cl   = lane & 15;
    const int gq   = lane >> 4;
    const int col  = g * 16 + cl;
    const int swz  = (cl & 7) << 4;
    const int rloc = wave * 16 + gq * 4;   // local row base (0..127)
    const int rg   = q * 128 + rloc;       // global row base

    unsigned* fl = flg + g * 32;      // one 128B line; words 0..3 = per-q flags

    // ---- A-fragments into registers once, LOGICAL (own-first) chunk order:
    // logical l <-> physical K-chunk (4q + l) & 15. All afrag[] indices are
    // LITERALS (rule #20: runtime-indexed arrays demote to scratch — R11).
    short8 afrag[16];
    {
        const int T = q * 8 + wave;    // global 16-row tile owned by this wave
#pragma unroll
        for (int l = 0; l < 16; ++l) {
            const int kphys = (4 * q + l) & 15;
            afrag[l] = *(const short8*)(Aw + ((size_t)(T * 16 + kphys) * 64 + lane) * 8);
        }
#pragma unroll
        for (int l = 0; l < 16; ++l)
            asm volatile("" : "+v"(afrag[l]));   // pin: no re-load, no remat
    }

    // ---- per-thread state: 4 rows x 1 col ----
    f32x4 X0, W;
    X0 = *(const f32x4*)(x + col * 512 + rg);     // Fortran x[col*512+row]
#pragma unroll
    for (int j = 0; j < 4; ++j) {
        const int row = rg + j;
        W[j] = r[row] + eps[row] * p[row * 1024 + col];
    }

    int ex = 0;   // exchange index 0..599

    // One RK stage. Sync skeleton: publish -> syncthreads(#1, drains all stores)
    // -> tid0 plain flag store -> own-K MFMA (hides spin) -> wave0 3-lane spin
    // -> syncthreads(#2) -> issue 3 peer pulls at once -> per-slice
    // {ds_write, lgkmcnt(0), raw s_barrier, 4 MFMA} pipeline: slice j's MFMA
    // hides slice j+1's in-flight load (raw barrier does NOT drain vmcnt).
    auto STAGE = [&](f32x4 Yv) -> f32x4 {
        char* buf = Ylds[ex & 1];
        // B-fragment for LOGICAL chunk l (physical (4q+l)&15); l is literal.
        auto bfrag = [&](int l) -> short8 {
            const int kphys = (4 * q + l) & 15;
            return *(const short8*)(buf + cl * 1024 + ((kphys * 64 + gq * 16) ^ swz));
        };

        unsigned lo = (unsigned)f2bf(Yv[0]) | ((unsigned)f2bf(Yv[1]) << 16);
        unsigned hi = (unsigned)f2bf(Yv[2]) | ((unsigned)f2bf(Yv[3]) << 16);
        uint2v u; u.x = lo; u.y = hi;
        *(uint2v*)(buf + cl * 1024 + ((rg * 2) ^ swz)) = u;        // own -> Ylds
        u64* slot = Ybuf + ((size_t)((ex & 1) * 64 + g) * 4 + q) * 512;
        __hip_atomic_store(slot + (cl * 32 + (rloc >> 2)),
                           (u64)lo | ((u64)hi << 32),
                           __ATOMIC_RELAXED, __HIP_MEMORY_SCOPE_AGENT);
        __syncthreads();   // #1: auto-drains vmcnt/lgkm -> own slice at LLC, own rows in buf
        if (tid == 0)      // single-writer release flag (ordered after drained data)
            __hip_atomic_store(fl + q, (unsigned)(ex + 1),
                               __ATOMIC_RELAXED, __HIP_MEMORY_SCOPE_AGENT);

        // ---- own-K overlap: logical chunks 0..3 (own 128 rows, in buf) ----
        f32x4 acc = (f32x4){0.f, 0.f, 0.f, 0.f};
#pragma unroll
        for (int l = 0; l < 4; ++l)
            acc = __builtin_amdgcn_mfma_f32_16x16x32_bf16(afrag[l], bfrag(l), acc, 0, 0, 0);

        const unsigned tgt = (unsigned)(ex + 1);
        if (wave == 0) {   // minimal spinners: 3 lanes, 3 words, one line
            for (;;) {
                unsigned v = tgt;
                if (lane < 3)
                    v = __hip_atomic_load(fl + ((q + 1 + lane) & 3),
                                          __ATOMIC_RELAXED, __HIP_MEMORY_SCOPE_AGENT);
                if (__all(v >= tgt)) break;
                __builtin_amdgcn_s_sleep(1);
            }
        }
        __syncthreads();   // #2: releases waves 1-7; drains spin loads
        asm volatile("" ::: "memory");

        // issue all 3 peer pulls up front (RTTs overlap)
        const int pcol = tid >> 5, prq = tid & 31;
        const u64* pb = Ybuf + (size_t)((ex & 1) * 64 + g) * 4 * 512;
        const int q1 = (q + 1) & 3, q2 = (q + 2) & 3, q3 = (q + 3) & 3;
        u64 v1 = __hip_atomic_load(pb + q1 * 512 + pcol * 32 + prq,
                                   __ATOMIC_RELAXED, __HIP_MEMORY_SCOPE_AGENT);
        u64 v2 = __hip_atomic_load(pb + q2 * 512 + pcol * 32 + prq,
                                   __ATOMIC_RELAXED, __HIP_MEMORY_SCOPE_AGENT);
        u64 v3 = __hip_atomic_load(pb + q3 * 512 + pcol * 32 + prq,
                                   __ATOMIC_RELAXED, __HIP_MEMORY_SCOPE_AGENT);

        // sub-stage 1: slice q1 -> LDS -> its 4 chunks (logical l=4..7)
        {
            uint2v w; w.x = (unsigned)v1; w.y = (unsigned)(v1 >> 32);
            const int prg = q1 * 128 + prq * 4;
            *(uint2v*)(buf + pcol * 1024 + ((prg * 2) ^ ((pcol & 7) << 4))) = w;
            asm volatile("s_waitcnt lgkmcnt(0)" ::: "memory");
            __builtin_amdgcn_sched_barrier(0);
            __builtin_amdgcn_s_barrier();          // raw: does NOT drain vmcnt (v2,v3 in flight)
#pragma unroll
            for (int l = 4; l < 8; ++l)
                acc = __builtin_amdgcn_mfma_f32_16x16x32_bf16(afrag[l], bfrag(l), acc, 0, 0, 0);
        }
        // sub-stage 2: slice q2 (l=8..11)
        {
            uint2v w; w.x = (unsigned)v2; w.y = (unsigned)(v2 >> 32);
            const int prg = q2 * 128 + prq * 4;
            *(uint2v*)(buf + pcol * 1024 + ((prg * 2) ^ ((pcol & 7) << 4))) = w;
            asm volatile("s_waitcnt lgkmcnt(0)" ::: "memory");
            __builtin_amdgcn_sched_barrier(0);
            __builtin_amdgcn_s_barrier();
#pragma unroll
            for (int l = 8; l < 12; ++l)
                acc = __builtin_amdgcn_mfma_f32_16x16x32_bf16(afrag[l], bfrag(l), acc, 0, 0, 0);
        }
        // sub-stage 3: slice q3 (l=12..15)
        {
            uint2v w; w.x = (unsigned)v3; w.y = (unsigned)(v3 >> 32);
            const int prg = q3 * 128 + prq * 4;
            *(uint2v*)(buf + pcol * 1024 + ((prg * 2) ^ ((pcol & 7) << 4))) = w;
            asm volatile("s_waitcnt lgkmcnt(0)" ::: "memory");
            __builtin_amdgcn_sched_barrier(0);
            __builtin_amdgcn_s_barrier();
#pragma unroll
            for (int l = 12; l < 16; ++l)
                acc = __builtin_amdgcn_mfma_f32_16x16x32_bf16(afrag[l], bfrag(l), acc, 0, 0, 0);
        }
        // no trailing barrier: next write to this buf is >=5 collective barriers away
        ++ex;
        return Yv * (W + acc);
    };

#pragma unroll 1
    for (int s = 0; s < NSTEPS; ++s) {
        f32x4 K1 = STAGE(X0);
        f32x4 K2 = STAGE(X0 + HSTEP * (A21 * K1));
        f32x4 K3 = STAGE(X0 + HSTEP * (A31 * K1 + A32 * K2));
        f32x4 K4 = STAGE(X0 + HSTEP * (A41 * K1 + A42 * K2 + A43 * K3));
        f32x4 K5 = STAGE(X0 + HSTEP * (A51 * K1 + A52 * K2 + A53 * K3 + A54 * K4));
        f32x4 K6 = STAGE(X0 + HSTEP * (A61 * K1 + A62 * K2 + A63 * K3 + A64 * K4 + A65 * K5));
        X0 = X0 + HSTEP * (B1 * K1 + B3 * K3 + B4 * K4 + B5 * K5 + B6 * K6);
    }

    // Fortran flatten: out[col*512 + row]
    *(f32x4*)(out + col * 512 + rg) = X0;
}

extern "C" void kernel_launch(void* const* d_in, const int* in_sizes, int n_in,
                              void* d_out, int out_size, void* d_ws, size_t ws_size,
                              hipStream_t stream)
{
    const float* x   = (const float*)d_in[0];
    const float* p   = (const float*)d_in[1];
    const float* r   = (const float*)d_in[2];
    const float* A   = (const float*)d_in[3];
    const float* eps = (const float*)d_in[4];
    float* out = (float*)d_out;

    short*    Aw   = (short*)d_ws;
    unsigned* flg  = (unsigned*)((char*)d_ws + WS_FLG);
    u64*      Ybuf = (u64*)((char*)d_ws + WS_YB);

    hipMemsetAsync(flg, 0, 8192, stream);                   // zero flag lines
    hipLaunchKernelGGL(pack_A_kernel, dim3(128), dim3(256), 0, stream, A, Aw);
    hipLaunchKernelGGL(mbpert_kernel, dim3(256), dim3(512), 0, stream,
                       x, p, r, eps, Aw, flg, Ybuf, out);
}